// Round 11
// baseline (1238.006 us; speedup 1.0000x reference)
//
#include <hip/hip_runtime.h>
#include <hip/hip_fp16.h>

// MoE top-2 SwiGLU, MI355X. Sparse grouped-GEMM, 256-aligned expert segments.
// GEMMs: BM=128/BN=256, 8 waves, 16x16x32 f16 MFMA. A staged via global_load_lds
// (0-conflict XOR swizzle, 4x8KB buffers, distance-3); B frags loaded DIRECTLY
// from global per wave (L2-resident panel) -> LDS 32 KB -> 2 blocks/CU for
// cross-block MFMA/DS overlap (m114). One barrier per K-step. VGPR<=128.
// gemm1: virtual-N=8192 (w1/w3 interleaved 16-col) -> silu*mul -> h fp16. ORD0.
// gemm2: h @ w2^T, split-K=2 (partials ybuf + reused-w13), ORD1. combine: gated sum.
// Front-end: fused cvt+router (1 launch), atomic-free ballot-scan scatter.

#define NTOK 8192
#define D_ 1024
#define F_ 4096
#define E_ 8
#define SLOT_CAP 18432  // 2*8192 + 8*256

using half8 = __attribute__((ext_vector_type(8))) _Float16;
using half4 = __attribute__((ext_vector_type(4))) _Float16;
using f32x4 = __attribute__((ext_vector_type(4))) float;

__device__ __forceinline__ void gload16(const void* g, void* l) {
  __builtin_amdgcn_global_load_lds((const __attribute__((address_space(1))) void*)g,
                                   (__attribute__((address_space(3))) void*)l, 16, 0, 0);
}

// ---------------- fused weight-convert + router (grid-split single launch) ----------------
// blocks [0,4096): w1,w3 -> w13 interleave. [4096,8192): w2 -> fp16.
// [8192,10240): router (4 tokens/block) + x -> fp16.
__global__ __launch_bounds__(256) void prep_kernel(
    const float* __restrict__ w1, const float* __restrict__ w3, const float* __restrict__ w2,
    const float* __restrict__ x, const float* __restrict__ rw, const float* __restrict__ rbias,
    _Float16* __restrict__ w13, _Float16* __restrict__ w2h, _Float16* __restrict__ x16,
    int* __restrict__ tok_e, float* __restrict__ tok_g) {
  int b = blockIdx.x;
  if (b < 4096) {
    for (int i = b * 256 + threadIdx.x; i < E_ * F_ * D_ / 4; i += 4096 * 256) {
      int d4 = i & 255;   // D/4 = 256
      int row = i >> 8;   // e*4096 + f
      int e = row >> 12, f = row & 4095;
      size_t vbase = ((size_t)e << 13) | ((size_t)(f >> 4) << 5) | (size_t)(f & 15);
      float4 v1 = ((const float4*)w1)[i];
      float4 v3 = ((const float4*)w3)[i];
      half4 h1, h3;
      h1.x = (_Float16)v1.x; h1.y = (_Float16)v1.y; h1.z = (_Float16)v1.z; h1.w = (_Float16)v1.w;
      h3.x = (_Float16)v3.x; h3.y = (_Float16)v3.y; h3.z = (_Float16)v3.z; h3.w = (_Float16)v3.w;
      ((half4*)w13)[vbase * 256 + d4] = h1;
      ((half4*)w13)[(vbase + 16) * 256 + d4] = h3;
    }
  } else if (b < 8192) {
    for (int i = (b - 4096) * 256 + threadIdx.x; i < E_ * D_ * F_ / 4; i += 4096 * 256) {
      float4 v = ((const float4*)w2)[i];
      half4 h;
      h.x = (_Float16)v.x; h.y = (_Float16)v.y; h.z = (_Float16)v.z; h.w = (_Float16)v.w;
      ((half4*)w2h)[i] = h;
    }
  } else {
    int wv = threadIdx.x >> 6, lane = threadIdx.x & 63;
    int t = (b - 8192) * 4 + wv;
    const float4* xr = (const float4*)(x + (size_t)t * D_);
    float acc[E_];
#pragma unroll
    for (int e = 0; e < E_; ++e) acc[e] = 0.f;
    for (int i = lane; i < D_ / 4; i += 64) {
      float4 xv = xr[i];
      half4 hx;
      hx.x = (_Float16)xv.x; hx.y = (_Float16)xv.y; hx.z = (_Float16)xv.z; hx.w = (_Float16)xv.w;
      ((half4*)(x16 + (size_t)t * D_))[i] = hx;
#pragma unroll
      for (int e = 0; e < E_; ++e) {
        float4 wv4 = ((const float4*)(rw + (size_t)e * D_))[i];
        acc[e] += xv.x * wv4.x + xv.y * wv4.y + xv.z * wv4.z + xv.w * wv4.w;
      }
    }
#pragma unroll
    for (int e = 0; e < E_; ++e) {
#pragma unroll
      for (int off = 32; off > 0; off >>= 1) acc[e] += __shfl_down(acc[e], off);
    }
    if (lane == 0) {
      float p[E_], mx = -1e30f;
#pragma unroll
      for (int e = 0; e < E_; ++e) { p[e] = acc[e] + rbias[e]; mx = fmaxf(mx, p[e]); }
#pragma unroll
      for (int e = 0; e < E_; ++e) p[e] = expf(p[e] - mx);
      int i0 = 0;
#pragma unroll
      for (int e = 1; e < E_; ++e) if (p[e] > p[i0]) i0 = e;
      int i1 = (i0 == 0) ? 1 : 0;
#pragma unroll
      for (int e = 0; e < E_; ++e) if (e != i0 && p[e] > p[i1]) i1 = e;
      float s = p[i0] + p[i1];
      tok_e[t * 2] = i0; tok_e[t * 2 + 1] = i1;
      tok_g[t * 2] = p[i0] / s; tok_g[t * 2 + 1] = p[i1] / s;
    }
  }
}

// ---------------- atomic-free ordered scatter (single block, 1024 thr) ----------------
__global__ __launch_bounds__(1024) void scatter_kernel(
    const int* __restrict__ tok_e, int* __restrict__ slot_token,
    int* __restrict__ slot_of, int* __restrict__ offs) {
  __shared__ int wcnt[16][E_];
  int t = threadIdx.x, lane = t & 63, wv = t >> 6;

  int total[E_];
#pragma unroll
  for (int e = 0; e < E_; ++e) total[e] = 0;
  for (int c = 0; c < NTOK * 2; c += 1024) {
    int ei = tok_e[c + t];
#pragma unroll
    for (int e = 0; e < E_; ++e) {
      unsigned long long m = __ballot(ei == e);
      if (lane == 0) wcnt[wv][e] = __popcll(m);
    }
    __syncthreads();
#pragma unroll
    for (int e = 0; e < E_; ++e) {
      int s = 0;
#pragma unroll
      for (int w2 = 0; w2 < 16; ++w2) s += wcnt[w2][e];
      total[e] += s;
    }
    __syncthreads();
  }
  int base[E_ + 1];
  {
    int o = 0;
#pragma unroll
    for (int e = 0; e < E_; ++e) { base[e] = o; o += ((total[e] + 255) >> 8) << 8; }
    base[E_] = o;
  }
  if (t <= E_) offs[t] = base[t];
#pragma unroll
  for (int e = 0; e < E_; ++e)
    for (int p = base[e] + total[e] + t; p < base[e + 1]; p += 1024) slot_token[p] = 0;

  int run[E_];
#pragma unroll
  for (int e = 0; e < E_; ++e) run[e] = 0;
  for (int c = 0; c < NTOK * 2; c += 1024) {
    int ei = tok_e[c + t];
    int rank = 0;
#pragma unroll
    for (int e = 0; e < E_; ++e) {
      unsigned long long m = __ballot(ei == e);
      if (lane == 0) wcnt[wv][e] = __popcll(m);
      if (ei == e) rank = __popcll(m & ((1ULL << lane) - 1ULL));
    }
    __syncthreads();
    int mybase = 0, wbase = 0;
    int tot[E_];
#pragma unroll
    for (int e = 0; e < E_; ++e) {
      int s = 0;
#pragma unroll
      for (int w2 = 0; w2 < 16; ++w2) {
        int v = wcnt[w2][e];
        if (e == ei && w2 < wv) wbase += v;
        s += v;
      }
      tot[e] = s;
      if (e == ei) mybase = base[e] + run[e];
    }
    int pos = mybase + wbase + rank;
    slot_token[pos] = (c + t) >> 1;
    slot_of[c + t] = pos;
#pragma unroll
    for (int e = 0; e < E_; ++e) run[e] += tot[e];
    __syncthreads();
  }
}

// ---------------- grouped GEMM: A via LDS (swizzled), B direct-to-reg ----------------
// BM=128, BN=256, 8 waves (2wr x 4wc), per-wave 64x64. LDS 32KB -> 2 blocks/CU.
template <int MODE, int ORD, int KSPLIT, int KD, int NBN, int RPX, int BEROWS>
__global__ __launch_bounds__(512, 4) void moe_gemm_kernel(
    const _Float16* __restrict__ Amat, const _Float16* __restrict__ Bmat,
    const int* __restrict__ slot_token, const int* __restrict__ offs,
    void* __restrict__ outp, void* __restrict__ outp2) {
  constexpr int BM = 128;
  constexpr int MROW = 4;            // 16-row m-frags per wave
  constexpr int BUFH = BM * 32;      // 4096 halves = 8 KB (A only)
  constexpr int KL = KD / KSPLIT;
  constexpr int NT = KL / 32;        // K-steps (multiple of 4, >= 8)
  __shared__ _Float16 lds[4 * BUFH]; // 32 KB

  int id = blockIdx.x;
  int xcd = id & 7, idx = id >> 3;  // grid = 8 * RPX * NBN
  int vr, nb;
  if constexpr (ORD == 0) {
    int band = idx / (8 * NBN);
    int i2 = idx - band * (8 * NBN);
    int rib = (RPX - band * 8) < 8 ? (RPX - band * 8) : 8;
    nb = i2 / rib;
    vr = xcd * RPX + band * 8 + (i2 - nb * rib);
  } else {
    nb = idx % NBN;
    vr = xcd * RPX + idx / NBN;
  }
  int rb = vr, ks = 0;
  if constexpr (KSPLIT == 2) { rb = vr >> 1; ks = vr & 1; }
  int row0 = rb * BM;
  if (row0 >= offs[E_]) return;
  int e = 0;
#pragma unroll
  for (int i = 1; i < E_; ++i) if (row0 >= offs[i]) e = i;
  int koff = ks * KL;

  int t = threadIdx.x, l = t & 63, w = t >> 6;
  int wr = w >> 2, wc = w & 3;
  int srow = t >> 2;                           // 0..127 staging row
  int gsrc8 = ((l & 3) ^ ((l >> 3) & 3)) * 8;  // pre-swizzled source k-granule
  int fr = l & 15, kg = l >> 4;

  const _Float16* aP;
  if constexpr (MODE == 0) {
    int tk = slot_token[row0 + srow];
    aP = Amat + (size_t)tk * KD + koff + gsrc8;
  } else {
    aP = Amat + (size_t)(row0 + srow) * KD + koff + gsrc8;
  }
  // B direct: wave (wc) covers cols nb*256 + wc*64 .. +64; lane reads row (+ni*16+fr)
  const _Float16* bP =
      Bmat + ((size_t)e * BEROWS + (size_t)nb * 256 + wc * 64 + fr) * KD + koff + (size_t)kg * 8;

  // proven 0-conflict LDS read pattern (A): 16-row frags, granule kg
  int swz8 = (kg ^ ((fr >> 1) & 3)) * 8;
  const int rA = (wr * 64 + fr) * 32 + swz8;

  half8 aF[4], bF[4];
  f32x4 acc[MROW][4];
#pragma unroll
  for (int m = 0; m < MROW; ++m)
#pragma unroll
    for (int n = 0; n < 4; ++n) acc[m][n] = (f32x4){0.f, 0.f, 0.f, 0.f};

  // prologue: stage A tiles 0,1,2; wait tile 0 (1,2 stay in flight)
#pragma unroll
  for (int tt = 0; tt < 3; ++tt) gload16(aP + tt * 32, &lds[tt * BUFH + w * 512]);
  asm volatile("s_waitcnt vmcnt(2)" ::: "memory");
  __builtin_amdgcn_s_barrier();
  __builtin_amdgcn_sched_barrier(0);
  aP += 96;  // in-loop stage of tile j+3 uses aP + j*32

#define STEPP(U, PRE, FIN)                                                        \
  {                                                                               \
    constexpr int bi_ = (U) & 3;                                                  \
    constexpr int bs_ = ((U) + 3) & 3;                                            \
    const _Float16* cb_ = &lds[bi_ * BUFH];                                       \
    bF[0] = *(const half8*)(bP + (U) * 32);                                       \
    bF[1] = *(const half8*)(bP + (U) * 32 + 16 * (size_t)KD);                     \
    bF[2] = *(const half8*)(bP + (U) * 32 + 32 * (size_t)KD);                     \
    bF[3] = *(const half8*)(bP + (U) * 32 + 48 * (size_t)KD);                     \
    if (PRE) gload16(aP + (U) * 32, &lds[bs_ * BUFH + w * 512]);                  \
    aF[0] = *(const half8*)(cb_ + rA);                                            \
    aF[1] = *(const half8*)(cb_ + rA + 512);                                      \
    aF[2] = *(const half8*)(cb_ + rA + 1024);                                     \
    aF[3] = *(const half8*)(cb_ + rA + 1536);                                     \
    __builtin_amdgcn_s_setprio(1);                                                \
    _Pragma("unroll") for (int mi = 0; mi < MROW; ++mi)                           \
    _Pragma("unroll") for (int ni = 0; ni < 4; ++ni)                              \
        acc[mi][ni] = __builtin_amdgcn_mfma_f32_16x16x32_f16(aF[mi], bF[ni],      \
                                                             acc[mi][ni], 0, 0, 0); \
    __builtin_amdgcn_s_setprio(0);                                                \
    if (!(FIN)) {                                                                 \
      asm volatile("s_waitcnt vmcnt(1)" ::: "memory");                            \
      __builtin_amdgcn_s_barrier();                                               \
      __builtin_amdgcn_sched_barrier(0);                                          \
    }                                                                             \
  }

  for (int j4 = 0; j4 < NT - 4; j4 += 4) {
    STEPP(0, true, false)
    STEPP(1, true, false)
    STEPP(2, true, false)
    STEPP(3, true, false)
    aP += 128; bP += 128;
  }
  // tail: steps NT-4 .. NT-1 (stage only at first; no barrier after last)
  STEPP(0, true, false)
  STEPP(1, false, false)
  STEPP(2, false, false)
  STEPP(3, false, true)
#undef STEPP

  // epilogue. C/D 16x16: col = lane&15, row = (lane>>4)*4 + i  [m89 verified]
  int q4 = kg * 4;
  if constexpr (MODE == 0) {
    _Float16* hb = (_Float16*)outp;
#pragma unroll
    for (int mi = 0; mi < MROW; ++mi) {
      size_t rbase = (size_t)(row0 + wr * 64 + mi * 16 + q4);
#pragma unroll
      for (int p = 0; p < 2; ++p) {
        int fc = nb * 128 + (wc * 2 + p) * 16 + fr;
#pragma unroll
        for (int i = 0; i < 4; ++i) {
          float gv = acc[mi][2 * p][i];
          float hv = gv / (1.f + __expf(-gv)) * acc[mi][2 * p + 1][i];
          hb[(rbase + i) * (size_t)F_ + fc] = (_Float16)hv;
        }
      }
    }
  } else {
    float* yb = (float*)(ks == 0 ? outp : outp2);
#pragma unroll
    for (int mi = 0; mi < MROW; ++mi) {
      size_t rbase = (size_t)(row0 + wr * 64 + mi * 16 + q4);
#pragma unroll
      for (int ni = 0; ni < 4; ++ni) {
        int col = nb * 256 + wc * 64 + ni * 16 + fr;
#pragma unroll
        for (int i = 0; i < 4; ++i)
          yb[(rbase + i) * (size_t)D_ + col] = acc[mi][ni][i];
      }
    }
  }
}

// ---------------- combine: out = g0*(y0a+y0b) + g1*(y1a+y1b) ----------------
__global__ __launch_bounds__(256) void combine_kernel(
    const float* __restrict__ ya, const float* __restrict__ yb2,
    const int* __restrict__ slot_of, const float* __restrict__ tok_g,
    float* __restrict__ out) {
  int t = blockIdx.x, i = threadIdx.x;
  int s0 = slot_of[t * 2], s1 = slot_of[t * 2 + 1];
  float g0 = tok_g[t * 2], g1 = tok_g[t * 2 + 1];
  float4 a0 = ((const float4*)(ya + (size_t)s0 * D_))[i];
  float4 a1 = ((const float4*)(yb2 + (size_t)s0 * D_))[i];
  float4 b0 = ((const float4*)(ya + (size_t)s1 * D_))[i];
  float4 b1 = ((const float4*)(yb2 + (size_t)s1 * D_))[i];
  float4 r;
  r.x = g0 * (a0.x + a1.x) + g1 * (b0.x + b1.x);
  r.y = g0 * (a0.y + a1.y) + g1 * (b0.y + b1.y);
  r.z = g0 * (a0.z + a1.z) + g1 * (b0.z + b1.z);
  r.w = g0 * (a0.w + a1.w) + g1 * (b0.w + b1.w);
  ((float4*)(out + (size_t)t * D_))[i] = r;
}

extern "C" void kernel_launch(void* const* d_in, const int* in_sizes, int n_in,
                              void* d_out, int out_size, void* d_ws, size_t ws_size,
                              hipStream_t stream) {
  const float* x  = (const float*)d_in[0];
  const float* rw = (const float*)d_in[1];
  const float* rbc = (const float*)d_in[2];
  const float* w1 = (const float*)d_in[3];
  const float* w2 = (const float*)d_in[4];  // dict order: w2 before w3
  const float* w3 = (const float*)d_in[5];
  float* out = (float*)d_out;

  char* ws = (char*)d_ws;
  size_t off = 0;
  auto take = [&](size_t bytes) {
    char* p = ws + off;
    off = (off + bytes + 255) & ~(size_t)255;
    return p;
  };
  _Float16* x16 = (_Float16*)take((size_t)NTOK * D_ * 2);
  _Float16* w13 = (_Float16*)take((size_t)E_ * 2 * F_ * D_ * 2);  // 128 MB
  _Float16* w2h = (_Float16*)take((size_t)E_ * D_ * F_ * 2);      // 64 MB
  _Float16* hbuf = (_Float16*)take((size_t)SLOT_CAP * F_ * 2);    // 151 MB
  float* ybuf = (float*)take((size_t)SLOT_CAP * D_ * 4);          // 75.5 MB
  int* slot_token = (int*)take((size_t)SLOT_CAP * 4);
  int* tok_e = (int*)take((size_t)NTOK * 2 * 4);
  float* tok_g = (float*)take((size_t)NTOK * 2 * 4);
  int* slot_of = (int*)take((size_t)NTOK * 2 * 4);
  int* offs = (int*)take((E_ + 1) * 4);
  // split-K partial #1 reuses w13's space (dead after gemm1; stream-serialized)
  float* ybuf2 = (float*)w13;

  prep_kernel<<<10240, 256, 0, stream>>>(w1, w3, w2, x, rw, rbc, w13, w2h, x16, tok_e, tok_g);
  scatter_kernel<<<1, 1024, 0, stream>>>(tok_e, slot_token, slot_of, offs);
  // gemm1: 128x256, M<=18432 x Nvirt=8192 x K=1024 -> grid 8*18*32, ORD0 (share B)
  moe_gemm_kernel<0, 0, 1, 1024, 32, 18, 8192><<<4608, 512, 0, stream>>>(
      x16, w13, slot_token, offs, (void*)hbuf, nullptr);
  // gemm2: 128x256, split-K=2, M<=18432 x N=1024 x K=4096 -> grid 8*36*4, ORD1 (share A)
  moe_gemm_kernel<1, 1, 2, 4096, 4, 36, 1024><<<1152, 512, 0, stream>>>(
      hbuf, w2h, slot_token, offs, (void*)ybuf, (void*)ybuf2);
  combine_kernel<<<NTOK, 256, 0, stream>>>(ybuf, ybuf2, slot_of, tok_g, out);
}

// Round 12
// 735.538 us; speedup vs baseline: 1.6831x; 1.6831x over previous
//
#include <hip/hip_runtime.h>
#include <hip/hip_fp16.h>

// MoE top-2 SwiGLU, MI355X. Sparse grouped-GEMM, 256-aligned expert segments.
// GEMMs (R9/R10-proven, restored after R11 B-direct regression): 256x256 tile,
// 8 waves, 16x16x32 f16 MFMA, 0-conflict XOR swizzle (pre-swizzled global src),
// 4 LDS buffers, distance-3 gload prefetch, 2-phase m201-style inner schedule,
// counted vmcnt (8/4/0) per K-step.
// gemm1: virtual-N=8192 (w1/w3 interleaved 16-col) -> silu*mul -> h fp16. ORD0.
// gemm2: h @ w2^T, split-K=2 (partials ybuf + reused-w13), ORD1. combine: gated sum.
// Front-end: single fused prep launch (w13/w2 convert + router + x16), atomic-free
// ballot-scan scatter. 5 launches total.

#define NTOK 8192
#define D_ 1024
#define F_ 4096
#define E_ 8
#define SLOT_CAP 18432  // 2*8192 + 8*256

using half8 = __attribute__((ext_vector_type(8))) _Float16;
using half4 = __attribute__((ext_vector_type(4))) _Float16;
using f32x4 = __attribute__((ext_vector_type(4))) float;

__device__ __forceinline__ void gload16(const void* g, void* l) {
  __builtin_amdgcn_global_load_lds((const __attribute__((address_space(1))) void*)g,
                                   (__attribute__((address_space(3))) void*)l, 16, 0, 0);
}

// ---------------- fused weight-convert + router (grid-split single launch) ----------------
// blocks [0,4096): w1,w3 -> w13 interleave. [4096,8192): w2 -> fp16.
// [8192,10240): router (4 tokens/block) + x -> fp16.
__global__ __launch_bounds__(256) void prep_kernel(
    const float* __restrict__ w1, const float* __restrict__ w3, const float* __restrict__ w2,
    const float* __restrict__ x, const float* __restrict__ rw, const float* __restrict__ rbias,
    _Float16* __restrict__ w13, _Float16* __restrict__ w2h, _Float16* __restrict__ x16,
    int* __restrict__ tok_e, float* __restrict__ tok_g) {
  int b = blockIdx.x;
  if (b < 4096) {
    for (int i = b * 256 + threadIdx.x; i < E_ * F_ * D_ / 4; i += 4096 * 256) {
      int d4 = i & 255;   // D/4 = 256
      int row = i >> 8;   // e*4096 + f
      int e = row >> 12, f = row & 4095;
      size_t vbase = ((size_t)e << 13) | ((size_t)(f >> 4) << 5) | (size_t)(f & 15);
      float4 v1 = ((const float4*)w1)[i];
      float4 v3 = ((const float4*)w3)[i];
      half4 h1, h3;
      h1.x = (_Float16)v1.x; h1.y = (_Float16)v1.y; h1.z = (_Float16)v1.z; h1.w = (_Float16)v1.w;
      h3.x = (_Float16)v3.x; h3.y = (_Float16)v3.y; h3.z = (_Float16)v3.z; h3.w = (_Float16)v3.w;
      ((half4*)w13)[vbase * 256 + d4] = h1;
      ((half4*)w13)[(vbase + 16) * 256 + d4] = h3;
    }
  } else if (b < 8192) {
    for (int i = (b - 4096) * 256 + threadIdx.x; i < E_ * D_ * F_ / 4; i += 4096 * 256) {
      float4 v = ((const float4*)w2)[i];
      half4 h;
      h.x = (_Float16)v.x; h.y = (_Float16)v.y; h.z = (_Float16)v.z; h.w = (_Float16)v.w;
      ((half4*)w2h)[i] = h;
    }
  } else {
    int wv = threadIdx.x >> 6, lane = threadIdx.x & 63;
    int t = (b - 8192) * 4 + wv;
    const float4* xr = (const float4*)(x + (size_t)t * D_);
    float acc[E_];
#pragma unroll
    for (int e = 0; e < E_; ++e) acc[e] = 0.f;
    for (int i = lane; i < D_ / 4; i += 64) {
      float4 xv = xr[i];
      half4 hx;
      hx.x = (_Float16)xv.x; hx.y = (_Float16)xv.y; hx.z = (_Float16)xv.z; hx.w = (_Float16)xv.w;
      ((half4*)(x16 + (size_t)t * D_))[i] = hx;
#pragma unroll
      for (int e = 0; e < E_; ++e) {
        float4 wv4 = ((const float4*)(rw + (size_t)e * D_))[i];
        acc[e] += xv.x * wv4.x + xv.y * wv4.y + xv.z * wv4.z + xv.w * wv4.w;
      }
    }
#pragma unroll
    for (int e = 0; e < E_; ++e) {
#pragma unroll
      for (int off = 32; off > 0; off >>= 1) acc[e] += __shfl_down(acc[e], off);
    }
    if (lane == 0) {
      float p[E_], mx = -1e30f;
#pragma unroll
      for (int e = 0; e < E_; ++e) { p[e] = acc[e] + rbias[e]; mx = fmaxf(mx, p[e]); }
#pragma unroll
      for (int e = 0; e < E_; ++e) p[e] = expf(p[e] - mx);
      int i0 = 0;
#pragma unroll
      for (int e = 1; e < E_; ++e) if (p[e] > p[i0]) i0 = e;
      int i1 = (i0 == 0) ? 1 : 0;
#pragma unroll
      for (int e = 0; e < E_; ++e) if (e != i0 && p[e] > p[i1]) i1 = e;
      float s = p[i0] + p[i1];
      tok_e[t * 2] = i0; tok_e[t * 2 + 1] = i1;
      tok_g[t * 2] = p[i0] / s; tok_g[t * 2 + 1] = p[i1] / s;
    }
  }
}

// ---------------- atomic-free ordered scatter (single block, 1024 thr) ----------------
__global__ __launch_bounds__(1024) void scatter_kernel(
    const int* __restrict__ tok_e, int* __restrict__ slot_token,
    int* __restrict__ slot_of, int* __restrict__ offs) {
  __shared__ int wcnt[16][E_];
  int t = threadIdx.x, lane = t & 63, wv = t >> 6;

  int total[E_];
#pragma unroll
  for (int e = 0; e < E_; ++e) total[e] = 0;
  for (int c = 0; c < NTOK * 2; c += 1024) {
    int ei = tok_e[c + t];
#pragma unroll
    for (int e = 0; e < E_; ++e) {
      unsigned long long m = __ballot(ei == e);
      if (lane == 0) wcnt[wv][e] = __popcll(m);
    }
    __syncthreads();
#pragma unroll
    for (int e = 0; e < E_; ++e) {
      int s = 0;
#pragma unroll
      for (int w2 = 0; w2 < 16; ++w2) s += wcnt[w2][e];
      total[e] += s;
    }
    __syncthreads();
  }
  int base[E_ + 1];
  {
    int o = 0;
#pragma unroll
    for (int e = 0; e < E_; ++e) { base[e] = o; o += ((total[e] + 255) >> 8) << 8; }
    base[E_] = o;
  }
  if (t <= E_) offs[t] = base[t];
#pragma unroll
  for (int e = 0; e < E_; ++e)
    for (int p = base[e] + total[e] + t; p < base[e + 1]; p += 1024) slot_token[p] = 0;

  int run[E_];
#pragma unroll
  for (int e = 0; e < E_; ++e) run[e] = 0;
  for (int c = 0; c < NTOK * 2; c += 1024) {
    int ei = tok_e[c + t];
    int rank = 0;
#pragma unroll
    for (int e = 0; e < E_; ++e) {
      unsigned long long m = __ballot(ei == e);
      if (lane == 0) wcnt[wv][e] = __popcll(m);
      if (ei == e) rank = __popcll(m & ((1ULL << lane) - 1ULL));
    }
    __syncthreads();
    int mybase = 0, wbase = 0;
    int tot[E_];
#pragma unroll
    for (int e = 0; e < E_; ++e) {
      int s = 0;
#pragma unroll
      for (int w2 = 0; w2 < 16; ++w2) {
        int v = wcnt[w2][e];
        if (e == ei && w2 < wv) wbase += v;
        s += v;
      }
      tot[e] = s;
      if (e == ei) mybase = base[e] + run[e];
    }
    int pos = mybase + wbase + rank;
    slot_token[pos] = (c + t) >> 1;
    slot_of[c + t] = pos;
#pragma unroll
    for (int e = 0; e < E_; ++e) run[e] += tot[e];
    __syncthreads();
  }
}

// ---------------- pipelined grouped GEMM (16x16x32 f16, BM=256, BN=256) ----------------
template <int MODE, int ORD, int KSPLIT, int KD, int NBN, int RPX, int BEROWS>
__global__ __launch_bounds__(512, 2) void moe_gemm_kernel(
    const _Float16* __restrict__ Amat, const _Float16* __restrict__ Bmat,
    const int* __restrict__ slot_token, const int* __restrict__ offs,
    void* __restrict__ outp, void* __restrict__ outp2) {
  constexpr int BM = 256;
  constexpr int MROW = 8;               // 16-row m-frags per wave
  constexpr int AH = BM * 32;           // A halves per buffer (8192)
  constexpr int BUFH = (BM + 256) * 32; // 16384 halves = 32 KB
  constexpr int KL = KD / KSPLIT;       // K span per block
  constexpr int NT = KL / 32;           // K-steps (multiple of 4, >= 8)
  __shared__ _Float16 lds[4 * BUFH];    // 128 KB

  int id = blockIdx.x;
  int xcd = id & 7, idx = id >> 3;  // grid = 8 * RPX * NBN
  int vr, nb;
  if constexpr (ORD == 0) {
    int band = idx / (8 * NBN);
    int i2 = idx - band * (8 * NBN);
    int rib = (RPX - band * 8) < 8 ? (RPX - band * 8) : 8;
    nb = i2 / rib;
    vr = xcd * RPX + band * 8 + (i2 - nb * rib);
  } else {
    nb = idx % NBN;
    vr = xcd * RPX + idx / NBN;
  }
  int rb = vr, ks = 0;
  if constexpr (KSPLIT == 2) { rb = vr >> 1; ks = vr & 1; }
  int row0 = rb * BM;
  if (row0 >= offs[E_]) return;
  int e = 0;
#pragma unroll
  for (int i = 1; i < E_; ++i) if (row0 >= offs[i]) e = i;
  int koff = ks * KL;

  int t = threadIdx.x, l = t & 63, w = t >> 6;
  int wr = w >> 2, wc = w & 3;
  int srow = t >> 2;                           // 0..127 staging row
  int gsrc8 = ((l & 3) ^ ((l >> 3) & 3)) * 8;  // pre-swizzled source k-granule

  const _Float16* aP0;
  const _Float16* aP1;
  if constexpr (MODE == 0) {
    int tk0 = slot_token[row0 + srow];
    int tk1 = slot_token[row0 + srow + 128];
    aP0 = Amat + (size_t)tk0 * KD + koff + gsrc8;
    aP1 = Amat + (size_t)tk1 * KD + koff + gsrc8;
  } else {
    aP0 = Amat + (size_t)(row0 + srow) * KD + koff + gsrc8;
    aP1 = Amat + (size_t)(row0 + srow + 128) * KD + koff + gsrc8;
  }
  const _Float16* b0P =
      Bmat + ((size_t)e * BEROWS + (size_t)nb * 256 + srow) * KD + koff + gsrc8;
  const _Float16* b1P = b0P + (size_t)128 * KD;

  // proven 0-conflict read pattern: 16-row frags, granule kg = l>>4
  int fr = l & 15, kg = l >> 4;
  int swz8 = (kg ^ ((fr >> 1) & 3)) * 8;
  const int rA = (wr * 128 + fr) * 32 + swz8;
  const int rB = AH + (wc * 64 + fr) * 32 + swz8;

  half8 aF[4];
  half8 bF[4];
  f32x4 acc[MROW][4];
#pragma unroll
  for (int m = 0; m < MROW; ++m)
#pragma unroll
    for (int n = 0; n < 4; ++n) acc[m][n] = (f32x4){0.f, 0.f, 0.f, 0.f};

  // prologue: stage tiles 0,1,2 into buf0..2; wait tile 0 (tiles 1,2 in flight)
#pragma unroll
  for (int tt = 0; tt < 3; ++tt) {
    gload16(aP0 + tt * 32, &lds[tt * BUFH + w * 512]);
    gload16(aP1 + tt * 32, &lds[tt * BUFH + 4096 + w * 512]);
    gload16(b0P + tt * 32, &lds[tt * BUFH + AH + w * 512]);
    gload16(b1P + tt * 32, &lds[tt * BUFH + AH + 4096 + w * 512]);
  }
  asm volatile("s_waitcnt vmcnt(8)" ::: "memory");
  __builtin_amdgcn_s_barrier();
  __builtin_amdgcn_sched_barrier(0);
  // advance source pointers to tile 3 (first in-loop staged tile)
  aP0 += 96; aP1 += 96; b0P += 96; b1P += 96;

#define MF16(BASE)                                                           \
  _Pragma("unroll") for (int mi = 0; mi < 4; ++mi)                           \
  _Pragma("unroll") for (int ni = 0; ni < 4; ++ni)                           \
      acc[(BASE) + mi][ni] = __builtin_amdgcn_mfma_f32_16x16x32_f16(         \
          aF[mi], bF[ni], acc[(BASE) + mi][ni], 0, 0, 0);

// One K=32 step = 2 m201-style phases. Reads issued pre-barrier; lgkmcnt(0)
// post-barrier -> DS-pipe drain overlaps other waves' MFMA region.
#define STEPP(U, PRE, WN)                                                         \
  {                                                                               \
    constexpr int bi_ = (U) & 3;                                                  \
    constexpr int bs_ = ((U) + 3) & 3;                                            \
    const _Float16* cb_ = &lds[bi_ * BUFH];                                       \
    if (PRE) {                                                                    \
      gload16(aP0 + (U) * 32, &lds[bs_ * BUFH + w * 512]);                        \
      gload16(aP1 + (U) * 32, &lds[bs_ * BUFH + 4096 + w * 512]);                 \
    }                                                                             \
    aF[0] = *(const half8*)(cb_ + rA);                                            \
    aF[1] = *(const half8*)(cb_ + rA + 512);                                      \
    aF[2] = *(const half8*)(cb_ + rA + 1024);                                     \
    aF[3] = *(const half8*)(cb_ + rA + 1536);                                     \
    bF[0] = *(const half8*)(cb_ + rB);                                            \
    bF[1] = *(const half8*)(cb_ + rB + 512);                                      \
    bF[2] = *(const half8*)(cb_ + rB + 1024);                                     \
    bF[3] = *(const half8*)(cb_ + rB + 1536);                                     \
    __builtin_amdgcn_sched_barrier(0);                                            \
    __builtin_amdgcn_s_barrier();                                                 \
    asm volatile("s_waitcnt lgkmcnt(0)" ::: "memory");                            \
    __builtin_amdgcn_sched_barrier(0);                                            \
    __builtin_amdgcn_s_setprio(1);                                                \
    MF16(0)                                                                       \
    __builtin_amdgcn_s_setprio(0);                                                \
    __builtin_amdgcn_sched_barrier(0);                                            \
    __builtin_amdgcn_s_barrier();                                                 \
    if (PRE) {                                                                    \
      gload16(b0P + (U) * 32, &lds[bs_ * BUFH + AH + w * 512]);                   \
      gload16(b1P + (U) * 32, &lds[bs_ * BUFH + AH + 4096 + w * 512]);            \
    }                                                                             \
    aF[0] = *(const half8*)(cb_ + rA + 2048);                                     \
    aF[1] = *(const half8*)(cb_ + rA + 2560);                                     \
    aF[2] = *(const half8*)(cb_ + rA + 3072);                                     \
    aF[3] = *(const half8*)(cb_ + rA + 3584);                                     \
    __builtin_amdgcn_sched_barrier(0);                                            \
    __builtin_amdgcn_s_barrier();                                                 \
    asm volatile("s_waitcnt lgkmcnt(0)" ::: "memory");                            \
    __builtin_amdgcn_sched_barrier(0);                                            \
    __builtin_amdgcn_s_setprio(1);                                                \
    MF16(4)                                                                       \
    __builtin_amdgcn_s_setprio(0);                                                \
    if ((WN) >= 0) {                                                              \
      asm volatile("s_waitcnt vmcnt(%0)" ::"i"((WN) >= 0 ? (WN) : 0) : "memory"); \
      __builtin_amdgcn_sched_barrier(0);                                          \
      __builtin_amdgcn_s_barrier();                                               \
      __builtin_amdgcn_sched_barrier(0);                                          \
    }                                                                             \
  }

  for (int j4 = 0; j4 < NT - 4; j4 += 4) {
    STEPP(0, true, 8)
    STEPP(1, true, 8)
    STEPP(2, true, 8)
    STEPP(3, true, 8)
    aP0 += 128; aP1 += 128; b0P += 128; b1P += 128;
  }
  // tail: steps NT-4 .. NT-1
  STEPP(0, true, 8)    // stages tile NT-1; tile NT-3 resident after
  STEPP(1, false, 4)   // tile NT-2 resident after
  STEPP(2, false, 0)   // tile NT-1 resident after
  STEPP(3, false, -1)  // last step, no trailing sync
#undef STEPP
#undef MF16

  // epilogue. C/D 16x16: col = lane&15, row = (lane>>4)*4 + i  [m89 verified]
  int q4 = kg * 4;
  if constexpr (MODE == 0) {
    _Float16* hb = (_Float16*)outp;
#pragma unroll
    for (int mi = 0; mi < MROW; ++mi) {
      size_t rbase = (size_t)(row0 + wr * 128 + mi * 16 + q4);
#pragma unroll
      for (int p = 0; p < 2; ++p) {
        int fc = nb * 128 + (wc * 2 + p) * 16 + fr;
#pragma unroll
        for (int i = 0; i < 4; ++i) {
          float gv = acc[mi][2 * p][i];
          float hv = gv / (1.f + __expf(-gv)) * acc[mi][2 * p + 1][i];
          hb[(rbase + i) * (size_t)F_ + fc] = (_Float16)hv;
        }
      }
    }
  } else {
    float* yb = (float*)(ks == 0 ? outp : outp2);
#pragma unroll
    for (int mi = 0; mi < MROW; ++mi) {
      size_t rbase = (size_t)(row0 + wr * 128 + mi * 16 + q4);
#pragma unroll
      for (int ni = 0; ni < 4; ++ni) {
        int col = nb * 256 + wc * 64 + ni * 16 + fr;
#pragma unroll
        for (int i = 0; i < 4; ++i)
          yb[(rbase + i) * (size_t)D_ + col] = acc[mi][ni][i];
      }
    }
  }
}

// ---------------- combine: out = g0*(y0a+y0b) + g1*(y1a+y1b) ----------------
__global__ __launch_bounds__(256) void combine_kernel(
    const float* __restrict__ ya, const float* __restrict__ yb2,
    const int* __restrict__ slot_of, const float* __restrict__ tok_g,
    float* __restrict__ out) {
  int t = blockIdx.x, i = threadIdx.x;
  int s0 = slot_of[t * 2], s1 = slot_of[t * 2 + 1];
  float g0 = tok_g[t * 2], g1 = tok_g[t * 2 + 1];
  float4 a0 = ((const float4*)(ya + (size_t)s0 * D_))[i];
  float4 a1 = ((const float4*)(yb2 + (size_t)s0 * D_))[i];
  float4 b0 = ((const float4*)(ya + (size_t)s1 * D_))[i];
  float4 b1 = ((const float4*)(yb2 + (size_t)s1 * D_))[i];
  float4 r;
  r.x = g0 * (a0.x + a1.x) + g1 * (b0.x + b1.x);
  r.y = g0 * (a0.y + a1.y) + g1 * (b0.y + b1.y);
  r.z = g0 * (a0.z + a1.z) + g1 * (b0.z + b1.z);
  r.w = g0 * (a0.w + a1.w) + g1 * (b0.w + b1.w);
  ((float4*)(out + (size_t)t * D_))[i] = r;
}

extern "C" void kernel_launch(void* const* d_in, const int* in_sizes, int n_in,
                              void* d_out, int out_size, void* d_ws, size_t ws_size,
                              hipStream_t stream) {
  const float* x  = (const float*)d_in[0];
  const float* rw = (const float*)d_in[1];
  const float* rbc = (const float*)d_in[2];
  const float* w1 = (const float*)d_in[3];
  const float* w2 = (const float*)d_in[4];  // dict order: w2 before w3
  const float* w3 = (const float*)d_in[5];
  float* out = (float*)d_out;

  char* ws = (char*)d_ws;
  size_t off = 0;
  auto take = [&](size_t bytes) {
    char* p = ws + off;
    off = (off + bytes + 255) & ~(size_t)255;
    return p;
  };
  _Float16* x16 = (_Float16*)take((size_t)NTOK * D_ * 2);
  _Float16* w13 = (_Float16*)take((size_t)E_ * 2 * F_ * D_ * 2);  // 128 MB
  _Float16* w2h = (_Float16*)take((size_t)E_ * D_ * F_ * 2);      // 64 MB
  _Float16* hbuf = (_Float16*)take((size_t)SLOT_CAP * F_ * 2);    // 151 MB
  float* ybuf = (float*)take((size_t)SLOT_CAP * D_ * 4);          // 75.5 MB
  int* slot_token = (int*)take((size_t)SLOT_CAP * 4);
  int* tok_e = (int*)take((size_t)NTOK * 2 * 4);
  float* tok_g = (float*)take((size_t)NTOK * 2 * 4);
  int* slot_of = (int*)take((size_t)NTOK * 2 * 4);
  int* offs = (int*)take((E_ + 1) * 4);
  // split-K partial #1 reuses w13's space (dead after gemm1; stream-serialized)
  float* ybuf2 = (float*)w13;

  prep_kernel<<<10240, 256, 0, stream>>>(w1, w3, w2, x, rw, rbc, w13, w2h, x16, tok_e, tok_g);
  scatter_kernel<<<1, 1024, 0, stream>>>(tok_e, slot_token, slot_of, offs);
  // gemm1: 256x256, M<=18432 x Nvirt=8192 x K=1024 -> grid 8*9*32, ORD0 (share B)
  moe_gemm_kernel<0, 0, 1, 1024, 32, 9, 8192><<<2304, 512, 0, stream>>>(
      x16, w13, slot_token, offs, (void*)hbuf, nullptr);
  // gemm2: 256x256, split-K=2, M<=18432 x N=1024 x K=4096 -> grid 8*18*4, ORD1 (share A)
  moe_gemm_kernel<1, 1, 2, 4096, 4, 18, 1024><<<576, 512, 0, stream>>>(
      hbuf, w2h, slot_token, offs, (void*)ybuf, (void*)ybuf2);
  combine_kernel<<<NTOK, 256, 0, stream>>>(ybuf, ybuf2, slot_of, tok_g, out);
}